// Round 11
// baseline (241.504 us; speedup 1.0000x reference)
//
#include <hip/hip_runtime.h>

typedef __bf16 bf16x8 __attribute__((ext_vector_type(8)));
typedef __bf16 bf16x4 __attribute__((ext_vector_type(4)));
typedef float  f32x4  __attribute__((ext_vector_type(4)));

#define MFMA16(a, b, c) __builtin_amdgcn_mfma_f32_16x16x32_bf16(a, b, c, 0, 0, 0)
// async global->LDS, 16B per lane; LDS dest = wave-uniform base + lane*16
#define GLL(gp, lp) __builtin_amdgcn_global_load_lds( \
    (__attribute__((address_space(1))) void*)(gp),    \
    (__attribute__((address_space(3))) void*)(lp), 16, 0, 0)
// Barrier with manual vmcnt (keeps N GLLs in flight across the barrier) AND
// lgkmcnt(0) so queued ds_reads complete before buffers are overwritten.
#define WAITBAR(N) asm volatile("s_waitcnt vmcnt(" #N ") lgkmcnt(0)\n\ts_barrier" ::: "memory")

// ---------------- prep: cast X (f32->bf16) + transpose both weights ----------
// flat grid 12288 x 256: blk < 8192 -> cast 1024 f32 of X; else transpose
// tile of w_qkv (bx<96) or w_out. Fuses 3 independent memory-bound launches.
__global__ __launch_bounds__(256) void prep_kernel(
    const float* __restrict__ x, __bf16* __restrict__ xb,
    const float* __restrict__ w_qkv, __bf16* __restrict__ wqkvt,
    const float* __restrict__ w_out, __bf16* __restrict__ woutt) {
  __shared__ float tile[32][33];
  const int blk = blockIdx.x;
  const int tid = threadIdx.x;
  if (blk < 8192) {
    int i = blk * 256 + tid;
    const float4 v = ((const float4*)x)[i];
    bf16x4 o = {(__bf16)v.x, (__bf16)v.y, (__bf16)v.z, (__bf16)v.w};
    ((bf16x4*)xb)[i] = o;
    return;
  }
  const int t = blk - 8192;          // 0..4095
  int bx = t >> 5;                   // 0..127
  const int by = t & 31;             // 0..31
  const float* in;
  __bf16* out;
  int cols;
  if (bx < 96) { in = w_qkv; out = wqkvt; cols = 3072; }
  else         { in = w_out; out = woutt; cols = 1024; bx -= 96; }
  const int tx = tid & 31, ty = tid >> 5;   // 32 x 8
  const int xcol = bx * 32 + tx;
  const int y0 = by * 32;
#pragma unroll
  for (int i = 0; i < 32; i += 8)
    tile[ty + i][tx] = in[(y0 + ty + i) * cols + xcol];
  __syncthreads();
  const int ox = y0 + tx;
  const int oy0 = bx * 32;
#pragma unroll
  for (int i = 0; i < 32; i += 8)
    out[(oy0 + ty + i) * 1024 + ox] = (__bf16)tile[tx][ty + i];
}

// ---------------- QKV GEMM: C[M,3072] = A[M,1024] * Bt[3072,1024]^T ----------
// 128x128 tile, BK=32, 3-buffer depth-2 pipeline, WAITBAR(4). (R8-proven.)
// Launched as TWO half-M dispatches (m_base 0 / 4096, 768 blocks each):
// identical schedule & numerics, 3 blocks/CU x exactly one round per dispatch;
// surfaces attn/out-proj/prep counters in the rocprof top-5 (diagnostic).
// XCD swizzle: each XCD owns 3 consecutive n-tiles (B-slice L2-resident).
#define QSCALE 0.045084220027780106f
__global__ __launch_bounds__(256) void gemm_bt_kernel(
    const __bf16* __restrict__ A, const __bf16* __restrict__ Bt,
    __bf16* __restrict__ qo, __bf16* __restrict__ ko, __bf16* __restrict__ vo,
    int m_base) {
  __shared__ __bf16 LDS[3][2][4096];  // [buf][A/B][128*32] = 48 KiB
  const int tid = threadIdx.x;
  const int id = blockIdx.x;
  const int xcd = id & 7, s = id >> 3;
  const int bx = xcd * 3 + s % 3;
  const int by = s / 3;
  const int m0 = m_base + by * 128, n0 = bx * 128;
  const int w = tid >> 6, lane = tid & 63;
  const int quad = lane >> 4, l15 = lane & 15;
  const int wm = (w >> 1) * 64, wn = (w & 1) * 64;
  f32x4 acc[4][4] = {};
  const int sr = tid >> 2;
  const int sc = (tid & 3) * 8;
  const __bf16* ag = A + (m0 + sr) * 1024 + sc;
  const __bf16* bg = Bt + (n0 + sr) * 1024 + sc;

  auto stage = [&](int T, int b) {
    const int kk = T * 32;
    GLL(ag + kk,             &LDS[b][0][0] + w * 512);
    GLL(ag + 64 * 1024 + kk, &LDS[b][0][0] + 2048 + w * 512);
    GLL(bg + kk,             &LDS[b][1][0] + w * 512);
    GLL(bg + 64 * 1024 + kk, &LDS[b][1][0] + 2048 + w * 512);
  };
  auto compute = [&](int b) {
    const __bf16* Asb = &LDS[b][0][0];
    const __bf16* Bsb = &LDS[b][1][0];
    bf16x8 af[4], bfr[4];
#pragma unroll
    for (int i = 0; i < 4; ++i)
      af[i] = *(const bf16x8*)(Asb + (wm + i * 16 + l15) * 32 + quad * 8);
#pragma unroll
    for (int j = 0; j < 4; ++j)
      bfr[j] = *(const bf16x8*)(Bsb + (wn + j * 16 + l15) * 32 + quad * 8);
#pragma unroll
    for (int i = 0; i < 4; ++i)
#pragma unroll
      for (int j = 0; j < 4; ++j)
        acc[i][j] = MFMA16(af[i], bfr[j], acc[i][j]);
  };

  // pipeline: tiles 0..31, tile t lives in buf t%3
  stage(0, 0);
  stage(1, 1);
  WAITBAR(4);                    // tile 0 ready (tile 1 still in flight)
  for (int g = 0; g < 10; ++g) {
    const int t = g * 3;
    stage(t + 2, 2); compute(0); WAITBAR(4);
    stage(t + 3, 0); compute(1); WAITBAR(4);
    stage(t + 4, 1); compute(2); WAITBAR(4);
  }
  compute(0);                    // tile 30
  asm volatile("s_waitcnt vmcnt(0) lgkmcnt(0)\n\ts_barrier" ::: "memory");
  compute(1);                    // tile 31
  __syncthreads();               // LDS free for epilogue scratch

  // ---- epilogue: wave cols = one tensor, one head ----
  const int gcw = n0 + wn;
  float* T = (float*)(&LDS[0][0][0]) + w * 1088;  // per-wave [16][68] f32
  const int which = gcw >> 10;
  const int h = (gcw & 1023) >> 6;
  if (which == 2) {
    // V: acc rows = consecutive tokens => packed bf16x4 stores into vt[.][d][n]
#pragma unroll
    for (int i = 0; i < 4; ++i) {
      int gm = m0 + wm + i * 16 + quad * 4;
      int b = gm >> 10, n = gm & 1023;
      __bf16* vb = vo + ((long)(b * 16 + h) * 64) * 1024 + n;
#pragma unroll
      for (int j = 0; j < 4; ++j) {
        int dd = j * 16 + l15;
        bf16x4 pv = {(__bf16)acc[i][j][0], (__bf16)acc[i][j][1],
                     (__bf16)acc[i][j][2], (__bf16)acc[i][j][3]};
        *(bf16x4*)(vb + (long)dd * 1024) = pv;
      }
    }
  } else {
    // Q/K: LDS transpose -> 16B coalesced stores
    __bf16* dst = (which == 0) ? qo : ko;
    const float scl = (which == 0) ? QSCALE : 1.0f;
#pragma unroll
    for (int i = 0; i < 4; ++i) {
#pragma unroll
      for (int j = 0; j < 4; ++j)
#pragma unroll
        for (int r = 0; r < 4; ++r)
          T[(quad * 4 + r) * 68 + j * 16 + l15] = acc[i][j][r];
      const float* Tr = T + l15 * 68 + quad * 16;
      f32x4 c0 = *(const f32x4*)(Tr);
      f32x4 c1 = *(const f32x4*)(Tr + 4);
      f32x4 c2 = *(const f32x4*)(Tr + 8);
      f32x4 c3 = *(const f32x4*)(Tr + 12);
      int gm = m0 + wm + i * 16 + l15;
      int b = gm >> 10, n = gm & 1023;
      __bf16* p = dst + ((long)((b * 16 + h) * 1024 + n)) * 64 + quad * 16;
      bf16x8 o0 = {(__bf16)(c0[0] * scl), (__bf16)(c0[1] * scl),
                   (__bf16)(c0[2] * scl), (__bf16)(c0[3] * scl),
                   (__bf16)(c1[0] * scl), (__bf16)(c1[1] * scl),
                   (__bf16)(c1[2] * scl), (__bf16)(c1[3] * scl)};
      bf16x8 o1 = {(__bf16)(c2[0] * scl), (__bf16)(c2[1] * scl),
                   (__bf16)(c2[2] * scl), (__bf16)(c2[3] * scl),
                   (__bf16)(c3[0] * scl), (__bf16)(c3[1] * scl),
                   (__bf16)(c3[2] * scl), (__bf16)(c3[3] * scl)};
      *(bf16x8*)p = o0;
      *(bf16x8*)(p + 8) = o1;
    }
  }
}

// ---------------- out-proj GEMM: out[M,1024] = A[M,1024]*Bt[1024,1024]^T + b --
// 128x64 tile, BK=32 => grid 1024 blocks, LDS 36 KB => 4 blocks/CU, one
// full-residency round. Wave-tile 64x32 (acc[4][2]); 3 GLLs/stage -> WAITBAR(3).
// M-major XCD swizzle: A-slice (2 MiB) and full B (2 MiB) L2-resident per XCD.
__global__ __launch_bounds__(256) void gemm_out_kernel(
    const __bf16* __restrict__ A, const __bf16* __restrict__ Bt,
    float* __restrict__ outp, const float* __restrict__ bias) {
  __shared__ __bf16 LDS[3][6144];  // per buf: A[128*32] | B[64*32] at +4096
  const int tid = threadIdx.x;
  const int id = blockIdx.x;
  const int xcd = id & 7, s = id >> 3;        // s in 0..127
  const int by = xcd * 8 + (s >> 4);          // 64 m-tiles, M-major per XCD
  const int bx = s & 15;                      // 16 n-tiles of 64
  const int m0 = by * 128, n0 = bx * 64;
  const int w = tid >> 6, lane = tid & 63;
  const int quad = lane >> 4, l15 = lane & 15;
  const int wm = (w >> 1) * 64, wn = (w & 1) * 32;
  f32x4 acc[4][2] = {};
  const int sr = tid >> 2;
  const int sc = (tid & 3) * 8;
  const __bf16* ag = A + (m0 + sr) * 1024 + sc;
  const __bf16* bg = Bt + (n0 + sr) * 1024 + sc;

  auto stage = [&](int T, int b) {
    const int kk = T * 32;
    GLL(ag + kk,             &LDS[b][0] + w * 512);
    GLL(ag + 64 * 1024 + kk, &LDS[b][0] + 2048 + w * 512);
    GLL(bg + kk,             &LDS[b][0] + 4096 + w * 512);  // B: 64 rows only
  };
  auto compute = [&](int b) {
    const __bf16* Asb = &LDS[b][0];
    const __bf16* Bsb = &LDS[b][0] + 4096;
    bf16x8 af[4], bfr[2];
#pragma unroll
    for (int i = 0; i < 4; ++i)
      af[i] = *(const bf16x8*)(Asb + (wm + i * 16 + l15) * 32 + quad * 8);
#pragma unroll
    for (int j = 0; j < 2; ++j)
      bfr[j] = *(const bf16x8*)(Bsb + (wn + j * 16 + l15) * 32 + quad * 8);
#pragma unroll
    for (int i = 0; i < 4; ++i)
#pragma unroll
      for (int j = 0; j < 2; ++j)
        acc[i][j] = MFMA16(af[i], bfr[j], acc[i][j]);
  };

  // pipeline: tiles 0..31, tile t lives in buf t%3; 3 GLLs/stage -> vmcnt(3)
  stage(0, 0);
  stage(1, 1);
  WAITBAR(3);                    // tile 0 ready (tile 1 still in flight)
  for (int g = 0; g < 10; ++g) {
    const int t = g * 3;
    stage(t + 2, 2); compute(0); WAITBAR(3);
    stage(t + 3, 0); compute(1); WAITBAR(3);
    stage(t + 4, 1); compute(2); WAITBAR(3);
  }
  compute(0);                    // tile 30
  asm volatile("s_waitcnt vmcnt(0) lgkmcnt(0)\n\ts_barrier" ::: "memory");
  compute(1);                    // tile 31
  __syncthreads();               // LDS free for epilogue scratch

  // ---- epilogue: per-wave LDS transpose -> full-line f32 stores + bias ----
  const int cb = n0 + wn;                       // wave's 32-col base
  float* T = (float*)(&LDS[0][0]) + w * 592;    // per-wave [16][36] f32
  f32x4 bv0 = *(const f32x4*)(bias + cb + quad * 8);
  f32x4 bv1 = *(const f32x4*)(bias + cb + quad * 8 + 4);
#pragma unroll
  for (int i = 0; i < 4; ++i) {
#pragma unroll
    for (int j = 0; j < 2; ++j)
#pragma unroll
      for (int r = 0; r < 4; ++r)
        T[(quad * 4 + r) * 36 + j * 16 + l15] = acc[i][j][r];
    const float* Tr = T + l15 * 36 + quad * 8;
    f32x4 v0 = *(const f32x4*)(Tr);
    f32x4 v1 = *(const f32x4*)(Tr + 4);
    v0 += bv0;
    v1 += bv1;
    int gm = m0 + wm + i * 16 + l15;
    float* p = outp + (long)gm * 1024 + cb + quad * 8;
    *(f32x4*)(p) = v0;
    *(f32x4*)(p + 4) = v1;
  }
}

// ---------------- attention, S^T formulation, no-max exp2 softmax ----------------
// grid: 1024 blocks. XCD swizzle: bh = blk & 127, qt = blk >> 7, so all 8
// q-tile blocks of a bh satisfy blk % 8 == bh % 8 -> same XCD -> K/V stay in
// that XCD's L2 (16 bh x 256 KB = 4 MB). KVBLK=128 (R4/R8-proven).
__global__ __launch_bounds__(256, 4) void attn_kernel(
    const __bf16* __restrict__ q, const __bf16* __restrict__ k,
    const __bf16* __restrict__ vt, __bf16* __restrict__ ao) {
  __shared__ __bf16 KV[2][128 * 64];  // [0]=Ks [j][d] swz, [1]=Vs [d][j] swz; epilogue f32 scratch
  __shared__ __bf16 Ps[4][32 * 32];   // per-wave P quarter [i32][j32]
  __bf16* const Ks = KV[0];
  __bf16* const Vs = KV[1];
  const int tid = threadIdx.x;
  const int bh = blockIdx.x & 127, qt = blockIdx.x >> 7;
  const int w = tid >> 6, lane = tid & 63;
  const int quad = lane >> 4, l15 = lane & 15;
  const int qrow = qt * 128 + w * 32;
  const __bf16* qb = q + (bh * 1024 + qrow) * 64;
  bf16x8 qf[2][2];
#pragma unroll
  for (int f = 0; f < 2; ++f) {
    qf[f][0] = *(const bf16x8*)(qb + (f * 16 + l15) * 64 + quad * 8);
    qf[f][1] = *(const bf16x8*)(qb + (f * 16 + l15) * 64 + 32 + quad * 8);
  }
  f32x4 o[2][4] = {};
  float rs0 = 0.f, rs1 = 0.f;
  const int krow = tid >> 3, kg8 = tid & 7;
  const __bf16* kg = k + (bh * 1024 + krow) * 64 + kg8 * 8;
  const int ksw = (kg8 ^ (krow & 7)) * 8;
  const int vrow = tid >> 2, vg4 = tid & 3;
  const __bf16* vg = vt + (bh * 64 + vrow) * 1024 + vg4 * 8;
  const int kfs0 = (quad ^ (l15 & 7)) * 8;
  const int kfs1 = ((4 + quad) ^ (l15 & 7)) * 8;
  __bf16* const pw = Ps[w];
  const int psw = quad ^ (l15 & 3);

  bf16x8 kvr[4], vvr[4];
#pragma unroll
  for (int p = 0; p < 4; ++p) kvr[p] = *(const bf16x8*)(kg + (p * 32) * 64);
#pragma unroll
  for (int p = 0; p < 4; ++p) vvr[p] = *(const bf16x8*)(vg + p * 32);

  for (int jt = 0; jt < 8; ++jt) {
    __syncthreads();               // prior compute done reading Ks/Vs
#pragma unroll
    for (int p = 0; p < 4; ++p)
      *(bf16x8*)(Ks + (krow + p * 32) * 64 + ksw) = kvr[p];
#pragma unroll
    for (int p = 0; p < 4; ++p)
      *(bf16x8*)(Vs + vrow * 128 + (((p * 4 + vg4) ^ (vrow & 15)) * 8)) = vvr[p];
    __syncthreads();
    if (jt < 7) {                  // issue next tile's loads; latency hides under compute
      const int j0n = (jt + 1) * 128;
#pragma unroll
      for (int p = 0; p < 4; ++p) kvr[p] = *(const bf16x8*)(kg + (j0n + p * 32) * 64);
#pragma unroll
      for (int p = 0; p < 4; ++p) vvr[p] = *(const bf16x8*)(vg + j0n + p * 32);
    }
#pragma unroll
    for (int Q = 0; Q < 4; ++Q) {
#pragma unroll
      for (int tl = 0; tl < 2; ++tl) {
        const int t = 2 * Q + tl;
        const __bf16* kr = Ks + (t * 16 + l15) * 64;
        bf16x8 kf0 = *(const bf16x8*)(kr + kfs0);
        bf16x8 kf1 = *(const bf16x8*)(kr + kfs1);
        f32x4 z0 = {}, z1 = {};
        __builtin_amdgcn_s_setprio(1);
        z0 = MFMA16(kf0, qf[0][0], z0);
        z0 = MFMA16(kf1, qf[0][1], z0);
        z1 = MFMA16(kf0, qf[1][0], z1);
        z1 = MFMA16(kf1, qf[1][1], z1);
        __builtin_amdgcn_s_setprio(0);
        const float p00 = __builtin_amdgcn_exp2f(z0[0]), p01 = __builtin_amdgcn_exp2f(z0[1]);
        const float p02 = __builtin_amdgcn_exp2f(z0[2]), p03 = __builtin_amdgcn_exp2f(z0[3]);
        const float p10 = __builtin_amdgcn_exp2f(z1[0]), p11 = __builtin_amdgcn_exp2f(z1[1]);
        const float p12 = __builtin_amdgcn_exp2f(z1[2]), p13 = __builtin_amdgcn_exp2f(z1[3]);
        rs0 += (p00 + p01) + (p02 + p03);
        rs1 += (p10 + p11) + (p12 + p13);
        const int g = (2 * tl + (quad >> 1)) ^ (l15 & 3);
        bf16x4 pa = {(__bf16)p00, (__bf16)p01, (__bf16)p02, (__bf16)p03};
        bf16x4 pb = {(__bf16)p10, (__bf16)p11, (__bf16)p12, (__bf16)p13};
        *(bf16x4*)(pw + l15 * 32 + g * 8 + (quad & 1) * 4) = pa;
        *(bf16x4*)(pw + (16 + l15) * 32 + g * 8 + (quad & 1) * 4) = pb;
      }
      bf16x8 pf0 = *(const bf16x8*)(pw + l15 * 32 + psw * 8);
      bf16x8 pf1 = *(const bf16x8*)(pw + (16 + l15) * 32 + psw * 8);
      __builtin_amdgcn_s_setprio(1);
#pragma unroll
      for (int dt = 0; dt < 4; ++dt) {
        bf16x8 vf = *(const bf16x8*)(Vs + (dt * 16 + l15) * 128 + (((Q * 4 + quad) ^ l15) * 8));
        o[0][dt] = MFMA16(pf0, vf, o[0][dt]);
        o[1][dt] = MFMA16(pf1, vf, o[1][dt]);
      }
      __builtin_amdgcn_s_setprio(0);
    }
  }
  rs0 += __shfl_xor(rs0, 16); rs0 += __shfl_xor(rs0, 32);
  rs1 += __shfl_xor(rs1, 16); rs1 += __shfl_xor(rs1, 32);
  __syncthreads();               // KV free for f32 scratch
  float* const T = (float*)KV + w * 1088;  // per-wave [16][68] f32
  const int b = bh >> 4, h = bh & 15;
  const int rr = lane >> 3, c8 = lane & 7;
#pragma unroll
  for (int f = 0; f < 2; ++f) {
    const float rsf = f ? rs1 : rs0;
#pragma unroll
    for (int dt = 0; dt < 4; ++dt)
#pragma unroll
      for (int r = 0; r < 4; ++r)
        T[(quad * 4 + r) * 68 + dt * 16 + l15] = o[f][dt][r];
#pragma unroll
    for (int h2 = 0; h2 < 2; ++h2) {
      const int row = h2 * 8 + rr;            // 0..15 local q-row
      const float inv = 1.0f / __shfl(rsf, row);
      const float* Tr = T + row * 68 + c8 * 8;
      const f32x4 a0 = *(const f32x4*)(Tr);
      const f32x4 a1 = *(const f32x4*)(Tr + 4);
      bf16x8 ov = {(__bf16)(a0[0] * inv), (__bf16)(a0[1] * inv),
                   (__bf16)(a0[2] * inv), (__bf16)(a0[3] * inv),
                   (__bf16)(a1[0] * inv), (__bf16)(a1[1] * inv),
                   (__bf16)(a1[2] * inv), (__bf16)(a1[3] * inv)};
      const long grow = (long)b * 1024 + qrow + f * 16 + row;
      *(bf16x8*)(ao + grow * 1024 + h * 64 + c8 * 8) = ov;  // 8 lanes = one full 128B line
    }
  }
}

// ---------------- launch ----------------
extern "C" void kernel_launch(void* const* d_in, const int* in_sizes, int n_in,
                              void* d_out, int out_size, void* d_ws, size_t ws_size,
                              hipStream_t stream) {
  const float* x = (const float*)d_in[0];      // [8192,1024]
  const float* w_qkv = (const float*)d_in[1];  // [1024,3072]
  const float* w_out = (const float*)d_in[2];  // [1024,1024]
  const float* b_out = (const float*)d_in[3];  // [1024]
  float* out = (float*)d_out;

  char* ws = (char*)d_ws;
  __bf16* xb    = (__bf16*)(ws);                 // 16 MiB
  __bf16* wqkvt = (__bf16*)(ws + 16777216);      // 6 MiB
  __bf16* woutt = (__bf16*)(ws + 23068672);      // 2 MiB
  __bf16* qw    = (__bf16*)(ws + 25165824);
  __bf16* kw    = (__bf16*)(ws + 41943040);
  __bf16* vw    = (__bf16*)(ws + 58720256);      // end = 75497472
  __bf16* ao    = xb;  // alias: xb dead after QKV GEMM

  prep_kernel<<<12288, 256, 0, stream>>>(x, xb, w_qkv, wqkvt, w_out, woutt);
  gemm_bt_kernel<<<768, 256, 0, stream>>>(xb, wqkvt, qw, kw, vw, 0);
  gemm_bt_kernel<<<768, 256, 0, stream>>>(xb, wqkvt, qw, kw, vw, 4096);
  attn_kernel<<<1024, 256, 0, stream>>>(qw, kw, vw, ao);
  gemm_out_kernel<<<1024, 256, 0, stream>>>(ao, woutt, out, b_out);
}

// Round 12
// 232.887 us; speedup vs baseline: 1.0370x; 1.0370x over previous
//
#include <hip/hip_runtime.h>

typedef __bf16 bf16x8 __attribute__((ext_vector_type(8)));
typedef __bf16 bf16x4 __attribute__((ext_vector_type(4)));
typedef float  f32x4  __attribute__((ext_vector_type(4)));

#define MFMA16(a, b, c) __builtin_amdgcn_mfma_f32_16x16x32_bf16(a, b, c, 0, 0, 0)
// async global->LDS, 16B per lane; LDS dest = wave-uniform base + lane*16
#define GLL(gp, lp) __builtin_amdgcn_global_load_lds( \
    (__attribute__((address_space(1))) void*)(gp),    \
    (__attribute__((address_space(3))) void*)(lp), 16, 0, 0)
// Barrier with manual vmcnt (keeps N GLLs in flight across the barrier) AND
// lgkmcnt(0) so queued ds_reads complete before buffers are overwritten.
#define WAITBAR(N) asm volatile("s_waitcnt vmcnt(" #N ") lgkmcnt(0)\n\ts_barrier" ::: "memory")

// ---------------- prep: cast X (f32->bf16) + transpose both weights ----------
// 3072 fat blocks (was 12288 tiny ones -> dispatch-bound):
//  blk <1024: cast X, 8 grid-stride float4 per thread (32 floats/thread)
//  1024..2559: w_qkv transpose, 64k x 32n tiles -> 128B read AND write lines
//  2560..3071: w_out transpose, same tiling
__global__ __launch_bounds__(256) void prep_kernel(
    const float* __restrict__ x, __bf16* __restrict__ xb,
    const float* __restrict__ w_qkv, __bf16* __restrict__ wqkvt,
    const float* __restrict__ w_out, __bf16* __restrict__ woutt) {
  __shared__ float tile[64][33];
  const int blk = blockIdx.x;
  const int tid = threadIdx.x;
  if (blk < 1024) {
    const int base = blk * 256 + tid;
#pragma unroll
    for (int it = 0; it < 8; ++it) {
      const int i = base + it * 262144;        // 1024*256 threads, 8 rounds = 2M float4
      const float4 v = ((const float4*)x)[i];
      bf16x4 o = {(__bf16)v.x, (__bf16)v.y, (__bf16)v.z, (__bf16)v.w};
      ((bf16x4*)xb)[i] = o;
    }
    return;
  }
  // out[n][k] = (bf16)in[k][n]; tile = 64 k-rows x 32 n-cols
  const float* in;
  __bf16* out;
  int cols, kt, nt;
  if (blk < 2560) { const int t = blk - 1024; in = w_qkv; out = wqkvt; cols = 3072; kt = t / 96; nt = t - kt * 96; }
  else            { const int t = blk - 2560; in = w_out; out = woutt; cols = 1024; kt = t >> 5; nt = t & 31; }
  const int k0 = kt * 64, n0 = nt * 32;
  const int tx = tid & 31, ty = tid >> 5;      // 32 x 8 read layout: 128B rows
#pragma unroll
  for (int i = 0; i < 64; i += 8)
    tile[ty + i][tx] = in[(k0 + ty + i) * cols + n0 + tx];
  __syncthreads();
  const int c = tid & 63, r0 = tid >> 6;       // 64 x 4 write layout: 128B rows
#pragma unroll
  for (int i = 0; i < 8; ++i) {
    const int r = i * 4 + r0;                  // 0..31
    out[(n0 + r) * 1024 + k0 + c] = (__bf16)tile[c][r];
  }
}

// ---------------- QKV GEMM: C[M,3072] = A[M,1024] * Bt[3072,1024]^T ----------
// 128x128 tile, BK=32, 3-buffer depth-2 pipeline, WAITBAR(4). (R8/R10-proven.)
// Single 1536-block dispatch (R11's half-M split cost ~6us of boundary drain).
// XCD swizzle: each XCD owns 3 consecutive n-tiles (B-slice L2-resident).
#define QSCALE 0.045084220027780106f
__global__ __launch_bounds__(256) void gemm_bt_kernel(
    const __bf16* __restrict__ A, const __bf16* __restrict__ Bt,
    __bf16* __restrict__ qo, __bf16* __restrict__ ko, __bf16* __restrict__ vo) {
  __shared__ __bf16 LDS[3][2][4096];  // [buf][A/B][128*32] = 48 KiB
  const int tid = threadIdx.x;
  const int id = blockIdx.x;
  const int xcd = id & 7, s = id >> 3;
  const int bx = xcd * 3 + s % 3;
  const int by = s / 3;
  const int m0 = by * 128, n0 = bx * 128;
  const int w = tid >> 6, lane = tid & 63;
  const int quad = lane >> 4, l15 = lane & 15;
  const int wm = (w >> 1) * 64, wn = (w & 1) * 64;
  f32x4 acc[4][4] = {};
  const int sr = tid >> 2;
  const int sc = (tid & 3) * 8;
  const __bf16* ag = A + (m0 + sr) * 1024 + sc;
  const __bf16* bg = Bt + (n0 + sr) * 1024 + sc;

  auto stage = [&](int T, int b) {
    const int kk = T * 32;
    GLL(ag + kk,             &LDS[b][0][0] + w * 512);
    GLL(ag + 64 * 1024 + kk, &LDS[b][0][0] + 2048 + w * 512);
    GLL(bg + kk,             &LDS[b][1][0] + w * 512);
    GLL(bg + 64 * 1024 + kk, &LDS[b][1][0] + 2048 + w * 512);
  };
  auto compute = [&](int b) {
    const __bf16* Asb = &LDS[b][0][0];
    const __bf16* Bsb = &LDS[b][1][0];
    bf16x8 af[4], bfr[4];
#pragma unroll
    for (int i = 0; i < 4; ++i)
      af[i] = *(const bf16x8*)(Asb + (wm + i * 16 + l15) * 32 + quad * 8);
#pragma unroll
    for (int j = 0; j < 4; ++j)
      bfr[j] = *(const bf16x8*)(Bsb + (wn + j * 16 + l15) * 32 + quad * 8);
#pragma unroll
    for (int i = 0; i < 4; ++i)
#pragma unroll
      for (int j = 0; j < 4; ++j)
        acc[i][j] = MFMA16(af[i], bfr[j], acc[i][j]);
  };

  // pipeline: tiles 0..31, tile t lives in buf t%3
  stage(0, 0);
  stage(1, 1);
  WAITBAR(4);                    // tile 0 ready (tile 1 still in flight)
  for (int g = 0; g < 10; ++g) {
    const int t = g * 3;
    stage(t + 2, 2); compute(0); WAITBAR(4);
    stage(t + 3, 0); compute(1); WAITBAR(4);
    stage(t + 4, 1); compute(2); WAITBAR(4);
  }
  compute(0);                    // tile 30
  asm volatile("s_waitcnt vmcnt(0) lgkmcnt(0)\n\ts_barrier" ::: "memory");
  compute(1);                    // tile 31
  __syncthreads();               // LDS free for epilogue scratch

  // ---- epilogue: wave cols = one tensor, one head ----
  const int gcw = n0 + wn;
  float* T = (float*)(&LDS[0][0][0]) + w * 1088;  // per-wave [16][68] f32
  const int which = gcw >> 10;
  const int h = (gcw & 1023) >> 6;
  if (which == 2) {
    // V: acc rows = consecutive tokens => packed bf16x4 stores into vt[.][d][n]
#pragma unroll
    for (int i = 0; i < 4; ++i) {
      int gm = m0 + wm + i * 16 + quad * 4;
      int b = gm >> 10, n = gm & 1023;
      __bf16* vb = vo + ((long)(b * 16 + h) * 64) * 1024 + n;
#pragma unroll
      for (int j = 0; j < 4; ++j) {
        int dd = j * 16 + l15;
        bf16x4 pv = {(__bf16)acc[i][j][0], (__bf16)acc[i][j][1],
                     (__bf16)acc[i][j][2], (__bf16)acc[i][j][3]};
        *(bf16x4*)(vb + (long)dd * 1024) = pv;
      }
    }
  } else {
    // Q/K: LDS transpose -> 16B coalesced stores
    __bf16* dst = (which == 0) ? qo : ko;
    const float scl = (which == 0) ? QSCALE : 1.0f;
#pragma unroll
    for (int i = 0; i < 4; ++i) {
#pragma unroll
      for (int j = 0; j < 4; ++j)
#pragma unroll
        for (int r = 0; r < 4; ++r)
          T[(quad * 4 + r) * 68 + j * 16 + l15] = acc[i][j][r];
      const float* Tr = T + l15 * 68 + quad * 16;
      f32x4 c0 = *(const f32x4*)(Tr);
      f32x4 c1 = *(const f32x4*)(Tr + 4);
      f32x4 c2 = *(const f32x4*)(Tr + 8);
      f32x4 c3 = *(const f32x4*)(Tr + 12);
      int gm = m0 + wm + i * 16 + l15;
      int b = gm >> 10, n = gm & 1023;
      __bf16* p = dst + ((long)((b * 16 + h) * 1024 + n)) * 64 + quad * 16;
      bf16x8 o0 = {(__bf16)(c0[0] * scl), (__bf16)(c0[1] * scl),
                   (__bf16)(c0[2] * scl), (__bf16)(c0[3] * scl),
                   (__bf16)(c1[0] * scl), (__bf16)(c1[1] * scl),
                   (__bf16)(c1[2] * scl), (__bf16)(c1[3] * scl)};
      bf16x8 o1 = {(__bf16)(c2[0] * scl), (__bf16)(c2[1] * scl),
                   (__bf16)(c2[2] * scl), (__bf16)(c2[3] * scl),
                   (__bf16)(c3[0] * scl), (__bf16)(c3[1] * scl),
                   (__bf16)(c3[2] * scl), (__bf16)(c3[3] * scl)};
      *(bf16x8*)p = o0;
      *(bf16x8*)(p + 8) = o1;
    }
  }
}

// ---------------- out-proj GEMM: out[M,1024] = A[M,1024]*Bt[1024,1024]^T + b --
// 128x64 tile, BK=32 => grid 1024 blocks, LDS 36 KB => 4 blocks/CU, one
// full-residency round. Wave-tile 64x32 (acc[4][2]); 3 GLLs/stage -> WAITBAR(3).
// M-major XCD swizzle: A-slice (2 MiB) and full B (2 MiB) L2-resident per XCD.
__global__ __launch_bounds__(256) void gemm_out_kernel(
    const __bf16* __restrict__ A, const __bf16* __restrict__ Bt,
    float* __restrict__ outp, const float* __restrict__ bias) {
  __shared__ __bf16 LDS[3][6144];  // per buf: A[128*32] | B[64*32] at +4096
  const int tid = threadIdx.x;
  const int id = blockIdx.x;
  const int xcd = id & 7, s = id >> 3;        // s in 0..127
  const int by = xcd * 8 + (s >> 4);          // 64 m-tiles, M-major per XCD
  const int bx = s & 15;                      // 16 n-tiles of 64
  const int m0 = by * 128, n0 = bx * 64;
  const int w = tid >> 6, lane = tid & 63;
  const int quad = lane >> 4, l15 = lane & 15;
  const int wm = (w >> 1) * 64, wn = (w & 1) * 32;
  f32x4 acc[4][2] = {};
  const int sr = tid >> 2;
  const int sc = (tid & 3) * 8;
  const __bf16* ag = A + (m0 + sr) * 1024 + sc;
  const __bf16* bg = Bt + (n0 + sr) * 1024 + sc;

  auto stage = [&](int T, int b) {
    const int kk = T * 32;
    GLL(ag + kk,             &LDS[b][0] + w * 512);
    GLL(ag + 64 * 1024 + kk, &LDS[b][0] + 2048 + w * 512);
    GLL(bg + kk,             &LDS[b][0] + 4096 + w * 512);  // B: 64 rows only
  };
  auto compute = [&](int b) {
    const __bf16* Asb = &LDS[b][0];
    const __bf16* Bsb = &LDS[b][0] + 4096;
    bf16x8 af[4], bfr[2];
#pragma unroll
    for (int i = 0; i < 4; ++i)
      af[i] = *(const bf16x8*)(Asb + (wm + i * 16 + l15) * 32 + quad * 8);
#pragma unroll
    for (int j = 0; j < 2; ++j)
      bfr[j] = *(const bf16x8*)(Bsb + (wn + j * 16 + l15) * 32 + quad * 8);
#pragma unroll
    for (int i = 0; i < 4; ++i)
#pragma unroll
      for (int j = 0; j < 2; ++j)
        acc[i][j] = MFMA16(af[i], bfr[j], acc[i][j]);
  };

  // pipeline: tiles 0..31, tile t lives in buf t%3; 3 GLLs/stage -> vmcnt(3)
  stage(0, 0);
  stage(1, 1);
  WAITBAR(3);                    // tile 0 ready (tile 1 still in flight)
  for (int g = 0; g < 10; ++g) {
    const int t = g * 3;
    stage(t + 2, 2); compute(0); WAITBAR(3);
    stage(t + 3, 0); compute(1); WAITBAR(3);
    stage(t + 4, 1); compute(2); WAITBAR(3);
  }
  compute(0);                    // tile 30
  asm volatile("s_waitcnt vmcnt(0) lgkmcnt(0)\n\ts_barrier" ::: "memory");
  compute(1);                    // tile 31
  __syncthreads();               // LDS free for epilogue scratch

  // ---- epilogue: per-wave LDS transpose -> full-line f32 stores + bias ----
  const int cb = n0 + wn;                       // wave's 32-col base
  float* T = (float*)(&LDS[0][0]) + w * 592;    // per-wave [16][36] f32
  f32x4 bv0 = *(const f32x4*)(bias + cb + quad * 8);
  f32x4 bv1 = *(const f32x4*)(bias + cb + quad * 8 + 4);
#pragma unroll
  for (int i = 0; i < 4; ++i) {
#pragma unroll
    for (int j = 0; j < 2; ++j)
#pragma unroll
      for (int r = 0; r < 4; ++r)
        T[(quad * 4 + r) * 36 + j * 16 + l15] = acc[i][j][r];
    const float* Tr = T + l15 * 36 + quad * 8;
    f32x4 v0 = *(const f32x4*)(Tr);
    f32x4 v1 = *(const f32x4*)(Tr + 4);
    v0 += bv0;
    v1 += bv1;
    int gm = m0 + wm + i * 16 + l15;
    float* p = outp + (long)gm * 1024 + cb + quad * 8;
    *(f32x4*)(p) = v0;
    *(f32x4*)(p + 4) = v1;
  }
}

// ---------------- attention, S^T formulation, no-max exp2 softmax ----------------
// grid: 1024 blocks. XCD swizzle: bh = blk & 127, qt = blk >> 7, so all 8
// q-tile blocks of a bh satisfy blk % 8 == bh % 8 -> same XCD -> K/V stay in
// that XCD's L2 (16 bh x 256 KB = 4 MB). KVBLK=128 (R4/R8-proven).
// Measured R11: 54.5us, MfmaUtil 24, VALUBusy 29, WRITE 21.5MB (healthy).
__global__ __launch_bounds__(256, 4) void attn_kernel(
    const __bf16* __restrict__ q, const __bf16* __restrict__ k,
    const __bf16* __restrict__ vt, __bf16* __restrict__ ao) {
  __shared__ __bf16 KV[2][128 * 64];  // [0]=Ks [j][d] swz, [1]=Vs [d][j] swz; epilogue f32 scratch
  __shared__ __bf16 Ps[4][32 * 32];   // per-wave P quarter [i32][j32]
  __bf16* const Ks = KV[0];
  __bf16* const Vs = KV[1];
  const int tid = threadIdx.x;
  const int bh = blockIdx.x & 127, qt = blockIdx.x >> 7;
  const int w = tid >> 6, lane = tid & 63;
  const int quad = lane >> 4, l15 = lane & 15;
  const int qrow = qt * 128 + w * 32;
  const __bf16* qb = q + (bh * 1024 + qrow) * 64;
  bf16x8 qf[2][2];
#pragma unroll
  for (int f = 0; f < 2; ++f) {
    qf[f][0] = *(const bf16x8*)(qb + (f * 16 + l15) * 64 + quad * 8);
    qf[f][1] = *(const bf16x8*)(qb + (f * 16 + l15) * 64 + 32 + quad * 8);
  }
  f32x4 o[2][4] = {};
  float rs0 = 0.f, rs1 = 0.f;
  const int krow = tid >> 3, kg8 = tid & 7;
  const __bf16* kg = k + (bh * 1024 + krow) * 64 + kg8 * 8;
  const int ksw = (kg8 ^ (krow & 7)) * 8;
  const int vrow = tid >> 2, vg4 = tid & 3;
  const __bf16* vg = vt + (bh * 64 + vrow) * 1024 + vg4 * 8;
  const int kfs0 = (quad ^ (l15 & 7)) * 8;
  const int kfs1 = ((4 + quad) ^ (l15 & 7)) * 8;
  __bf16* const pw = Ps[w];
  const int psw = quad ^ (l15 & 3);

  bf16x8 kvr[4], vvr[4];
#pragma unroll
  for (int p = 0; p < 4; ++p) kvr[p] = *(const bf16x8*)(kg + (p * 32) * 64);
#pragma unroll
  for (int p = 0; p < 4; ++p) vvr[p] = *(const bf16x8*)(vg + p * 32);

  for (int jt = 0; jt < 8; ++jt) {
    __syncthreads();               // prior compute done reading Ks/Vs
#pragma unroll
    for (int p = 0; p < 4; ++p)
      *(bf16x8*)(Ks + (krow + p * 32) * 64 + ksw) = kvr[p];
#pragma unroll
    for (int p = 0; p < 4; ++p)
      *(bf16x8*)(Vs + vrow * 128 + (((p * 4 + vg4) ^ (vrow & 15)) * 8)) = vvr[p];
    __syncthreads();
    if (jt < 7) {                  // issue next tile's loads; latency hides under compute
      const int j0n = (jt + 1) * 128;
#pragma unroll
      for (int p = 0; p < 4; ++p) kvr[p] = *(const bf16x8*)(kg + (j0n + p * 32) * 64);
#pragma unroll
      for (int p = 0; p < 4; ++p) vvr[p] = *(const bf16x8*)(vg + j0n + p * 32);
    }
#pragma unroll
    for (int Q = 0; Q < 4; ++Q) {
#pragma unroll
      for (int tl = 0; tl < 2; ++tl) {
        const int t = 2 * Q + tl;
        const __bf16* kr = Ks + (t * 16 + l15) * 64;
        bf16x8 kf0 = *(const bf16x8*)(kr + kfs0);
        bf16x8 kf1 = *(const bf16x8*)(kr + kfs1);
        f32x4 z0 = {}, z1 = {};
        __builtin_amdgcn_s_setprio(1);
        z0 = MFMA16(kf0, qf[0][0], z0);
        z0 = MFMA16(kf1, qf[0][1], z0);
        z1 = MFMA16(kf0, qf[1][0], z1);
        z1 = MFMA16(kf1, qf[1][1], z1);
        __builtin_amdgcn_s_setprio(0);
        const float p00 = __builtin_amdgcn_exp2f(z0[0]), p01 = __builtin_amdgcn_exp2f(z0[1]);
        const float p02 = __builtin_amdgcn_exp2f(z0[2]), p03 = __builtin_amdgcn_exp2f(z0[3]);
        const float p10 = __builtin_amdgcn_exp2f(z1[0]), p11 = __builtin_amdgcn_exp2f(z1[1]);
        const float p12 = __builtin_amdgcn_exp2f(z1[2]), p13 = __builtin_amdgcn_exp2f(z1[3]);
        rs0 += (p00 + p01) + (p02 + p03);
        rs1 += (p10 + p11) + (p12 + p13);
        const int g = (2 * tl + (quad >> 1)) ^ (l15 & 3);
        bf16x4 pa = {(__bf16)p00, (__bf16)p01, (__bf16)p02, (__bf16)p03};
        bf16x4 pb = {(__bf16)p10, (__bf16)p11, (__bf16)p12, (__bf16)p13};
        *(bf16x4*)(pw + l15 * 32 + g * 8 + (quad & 1) * 4) = pa;
        *(bf16x4*)(pw + (16 + l15) * 32 + g * 8 + (quad & 1) * 4) = pb;
      }
      bf16x8 pf0 = *(const bf16x8*)(pw + l15 * 32 + psw * 8);
      bf16x8 pf1 = *(const bf16x8*)(pw + (16 + l15) * 32 + psw * 8);
      __builtin_amdgcn_s_setprio(1);
#pragma unroll
      for (int dt = 0; dt < 4; ++dt) {
        bf16x8 vf = *(const bf16x8*)(Vs + (dt * 16 + l15) * 128 + (((Q * 4 + quad) ^ l15) * 8));
        o[0][dt] = MFMA16(pf0, vf, o[0][dt]);
        o[1][dt] = MFMA16(pf1, vf, o[1][dt]);
      }
      __builtin_amdgcn_s_setprio(0);
    }
  }
  rs0 += __shfl_xor(rs0, 16); rs0 += __shfl_xor(rs0, 32);
  rs1 += __shfl_xor(rs1, 16); rs1 += __shfl_xor(rs1, 32);
  __syncthreads();               // KV free for f32 scratch
  float* const T = (float*)KV + w * 1088;  // per-wave [16][68] f32
  const int b = bh >> 4, h = bh & 15;
  const int rr = lane >> 3, c8 = lane & 7;
#pragma unroll
  for (int f = 0; f < 2; ++f) {
    const float rsf = f ? rs1 : rs0;
#pragma unroll
    for (int dt = 0; dt < 4; ++dt)
#pragma unroll
      for (int r = 0; r < 4; ++r)
        T[(quad * 4 + r) * 68 + dt * 16 + l15] = o[f][dt][r];
#pragma unroll
    for (int h2 = 0; h2 < 2; ++h2) {
      const int row = h2 * 8 + rr;            // 0..15 local q-row
      const float inv = 1.0f / __shfl(rsf, row);
      const float* Tr = T + row * 68 + c8 * 8;
      const f32x4 a0 = *(const f32x4*)(Tr);
      const f32x4 a1 = *(const f32x4*)(Tr + 4);
      bf16x8 ov = {(__bf16)(a0[0] * inv), (__bf16)(a0[1] * inv),
                   (__bf16)(a0[2] * inv), (__bf16)(a0[3] * inv),
                   (__bf16)(a1[0] * inv), (__bf16)(a1[1] * inv),
                   (__bf16)(a1[2] * inv), (__bf16)(a1[3] * inv)};
      const long grow = (long)b * 1024 + qrow + f * 16 + row;
      *(bf16x8*)(ao + grow * 1024 + h * 64 + c8 * 8) = ov;  // 8 lanes = one full 128B line
    }
  }
}

// ---------------- launch ----------------
extern "C" void kernel_launch(void* const* d_in, const int* in_sizes, int n_in,
                              void* d_out, int out_size, void* d_ws, size_t ws_size,
                              hipStream_t stream) {
  const float* x = (const float*)d_in[0];      // [8192,1024]
  const float* w_qkv = (const float*)d_in[1];  // [1024,3072]
  const float* w_out = (const float*)d_in[2];  // [1024,1024]
  const float* b_out = (const float*)d_in[3];  // [1024]
  float* out = (float*)d_out;

  char* ws = (char*)d_ws;
  __bf16* xb    = (__bf16*)(ws);                 // 16 MiB
  __bf16* wqkvt = (__bf16*)(ws + 16777216);      // 6 MiB
  __bf16* woutt = (__bf16*)(ws + 23068672);      // 2 MiB
  __bf16* qw    = (__bf16*)(ws + 25165824);
  __bf16* kw    = (__bf16*)(ws + 41943040);
  __bf16* vw    = (__bf16*)(ws + 58720256);      // end = 75497472
  __bf16* ao    = xb;  // alias: xb dead after QKV GEMM

  prep_kernel<<<3072, 256, 0, stream>>>(x, xb, w_qkv, wqkvt, w_out, woutt);
  gemm_bt_kernel<<<1536, 256, 0, stream>>>(xb, wqkvt, qw, kw, vw);
  attn_kernel<<<1024, 256, 0, stream>>>(qw, kw, vw, ao);
  gemm_out_kernel<<<1024, 256, 0, stream>>>(ao, woutt, out, b_out);
}